// Round 6
// baseline (114.241 us; speedup 1.0000x reference)
//
#include <hip/hip_runtime.h>
#include <hip/hip_bf16.h>
#include <cstddef>

#define BB 4
#define CC 64
#define UU 5
#define VV 5
#define HH 64
#define WW 64
#define NIJ (69*69)   // 4761

__device__ __forceinline__ float rdlane(float v, int l) {
    return __uint_as_float((unsigned)__builtin_amdgcn_readlane((int)__float_as_uint(v), l));
}
__device__ __forceinline__ float sum4(float4 a) { return (a.x+a.y)+(a.z+a.w); }

// ---------------------------------------------------------------------------
// K1: grid = B*C*U = 1280 blocks, 512 threads. Pure-VALU inner loop (no
// shuffles); all cross-lane reduction deferred to block end.
//   part_hw[(b*5+u)*64+c][h*16+wq]  f4, UNSCALED sum over v
//   part_vw[(b*5+u)*64+c][v*16+wq]  f4, UNSCALED col sums (over h)
//   part_uv[((b*5+v)*5+u)*64+c]     UNSCALED tile totals
// part_* live in d_out (scratch until k3 rewrites it).
// ---------------------------------------------------------------------------
__global__ __launch_bounds__(512) void k1_means(const float* __restrict__ x,
        float* __restrict__ part_hw, float* __restrict__ part_vw,
        float* __restrict__ part_uv) {
    const int blk = blockIdx.x;       // bc*5 + u
    const int bc  = blk / 5;
    const int u   = blk % 5;
    const int b   = bc >> 6;
    const int c   = bc & 63;
    const int pidx = (b*5 + u)*64 + c;
    const float4* xt = (const float4*)x + (size_t)bc * 25600 + (size_t)u * 5120;
    const int t    = threadIdx.x;     // 0..511
    const int wave = t >> 6;
    const int lane = t & 63;

    __shared__ float4 vw_lds[8][5][16];

    float4 A[5], B[5];
    #pragma unroll
    for (int v = 0; v < 5; ++v) {
        A[v] = xt[v*1024 + t];
        B[v] = xt[v*1024 + 512 + t];
    }

    float4 hw0 = make_float4(0.f,0.f,0.f,0.f);
    float4 hw1 = make_float4(0.f,0.f,0.f,0.f);
    float4 cs[5];
    #pragma unroll
    for (int v = 0; v < 5; ++v) {
        float4 a = A[v], d = B[v];
        hw0.x += a.x; hw0.y += a.y; hw0.z += a.z; hw0.w += a.w;
        hw1.x += d.x; hw1.y += d.y; hw1.z += d.z; hw1.w += d.w;
        cs[v].x = a.x + d.x; cs[v].y = a.y + d.y;
        cs[v].z = a.z + d.z; cs[v].w = a.w + d.w;
    }

    // hw partial out (unscaled), contiguous 16KB
    float4* ph4 = (float4*)part_hw + (size_t)pidx * 1024;
    ph4[t]       = hw0;
    ph4[512 + t] = hw1;

    // deferred column reduce: per v, sum over this wave's 8 h-rows
    #pragma unroll
    for (int v = 0; v < 5; ++v) {
        float4 s = cs[v];
        s.x += __shfl_xor(s.x, 16); s.y += __shfl_xor(s.y, 16);
        s.z += __shfl_xor(s.z, 16); s.w += __shfl_xor(s.w, 16);
        s.x += __shfl_xor(s.x, 32); s.y += __shfl_xor(s.y, 32);
        s.z += __shfl_xor(s.z, 32); s.w += __shfl_xor(s.w, 32);
        if (lane < 16) vw_lds[wave][v][lane] = s;
    }
    __syncthreads();

    if (t < 80) {   // v = t>>4, wq = t&15: cross-wave reduce
        const int v = t >> 4;
        float4 s = vw_lds[0][v][t & 15];
        #pragma unroll
        for (int w8 = 1; w8 < 8; ++w8) {
            float4 p = vw_lds[w8][v][t & 15];
            s.x += p.x; s.y += p.y; s.z += p.z; s.w += p.w;
        }
        ((float4*)part_vw)[(size_t)pidx*80 + t] = s;
        // derive uv total: sum s over w
        float hs = sum4(s);
        hs += __shfl_xor(hs, 1); hs += __shfl_xor(hs, 2);
        hs += __shfl_xor(hs, 4); hs += __shfl_xor(hs, 8);
        if ((t & 15) == 0)
            part_uv[((size_t)(b*5 + v)*5 + u)*64 + c] = hs;
    }
}

// ---------------------------------------------------------------------------
// K1b_top: one block per (b,h) = 256 blocks, 512 threads.
// Sums part_hw over u (256B-contiguous reads), derives uh in-register,
// transposes c, writes grid_t row h (69 cols: 64 hw + 5 uh).
// ---------------------------------------------------------------------------
__global__ __launch_bounds__(512) void k1b_top(
        const float* __restrict__ part_hw, float* __restrict__ grid_t) {
    __shared__ float tile[64][68];
    const int blk = blockIdx.x;
    const int b = blk >> 6;
    const int h = blk & 63;
    const int t = threadIdx.x;        // 0..511
    const int c = t >> 3;             // 0..63
    const int q = t & 7;              // 0..7

    float4 acc0 = make_float4(0.f,0.f,0.f,0.f);
    float4 acc1 = make_float4(0.f,0.f,0.f,0.f);
    float uhv[5];
    #pragma unroll
    for (int u = 0; u < 5; ++u) {
        const float4* src = (const float4*)part_hw
            + ((size_t)((b*5 + u)*64 + c)) * 1024 + h*16;
        float4 p0 = src[q];
        float4 p1 = src[8 + q];
        acc0.x += p0.x; acc0.y += p0.y; acc0.z += p0.z; acc0.w += p0.w;
        acc1.x += p1.x; acc1.y += p1.y; acc1.z += p1.z; acc1.w += p1.w;
        float uu = sum4(p0) + sum4(p1);
        uu += __shfl_xor(uu, 1); uu += __shfl_xor(uu, 2); uu += __shfl_xor(uu, 4);
        uhv[u] = uu;                  // valid at q==0
    }
    const float s25 = 1.f/25.f;
    const int w0 = q*4, w1 = 32 + q*4;
    tile[w0+0][c] = acc0.x*s25; tile[w0+1][c] = acc0.y*s25;
    tile[w0+2][c] = acc0.z*s25; tile[w0+3][c] = acc0.w*s25;
    tile[w1+0][c] = acc1.x*s25; tile[w1+1][c] = acc1.y*s25;
    tile[w1+2][c] = acc1.z*s25; tile[w1+3][c] = acc1.w*s25;

    // uh border (before barrier: register data, disjoint addresses)
    if (q == 0) {
        #pragma unroll
        for (int u = 0; u < 5; ++u)
            grid_t[((size_t)b*NIJ + h*69 + 64 + u)*64 + c] = uhv[u] * (1.f/320.f);
    }
    __syncthreads();

    float4* dst4 = (float4*)grid_t + ((size_t)b*NIJ + h*69) * 16;
    #pragma unroll
    for (int k = 0; k < 2; ++k) {
        const int oidx = k*512 + t;   // 0..1023
        const int w = oidx >> 4, cq = (oidx & 15) * 4;
        float4 v;
        v.x = tile[w][cq]; v.y = tile[w][cq+1];
        v.z = tile[w][cq+2]; v.w = tile[w][cq+3];
        dst4[oidx] = v;
    }
}

// ---------------------------------------------------------------------------
// K1b_bot: one block per (b,v) = 20 blocks, 256 threads.
// Sums part_vw over u, transposes, writes grid_t row 64+v (64 vw + 5 uv).
// ---------------------------------------------------------------------------
__global__ __launch_bounds__(256) void k1b_bot(
        const float* __restrict__ part_vw, const float* __restrict__ part_uv,
        float* __restrict__ grid_t) {
    __shared__ float tile[64][68];
    const int blk = blockIdx.x;       // b*5 + v
    const int b = blk / 5;
    const int v = blk % 5;
    const int t = threadIdx.x;        // 0..255
    const int c = t >> 2;
    const int qs = t & 3;

    #pragma unroll
    for (int j = 0; j < 4; ++j) {
        const int wq = 4*j + qs;
        float4 acc = make_float4(0.f,0.f,0.f,0.f);
        #pragma unroll
        for (int u = 0; u < 5; ++u) {
            float4 p = ((const float4*)part_vw)
                [((size_t)((b*5 + u)*64 + c))*80 + v*16 + wq];
            acc.x += p.x; acc.y += p.y; acc.z += p.z; acc.w += p.w;
        }
        const int w = wq * 4;
        const float sc = 1.f/320.f;
        tile[w+0][c] = acc.x*sc; tile[w+1][c] = acc.y*sc;
        tile[w+2][c] = acc.z*sc; tile[w+3][c] = acc.w*sc;
    }
    __syncthreads();

    const int i = 64 + v;
    float4* dst4 = (float4*)grid_t + ((size_t)b*NIJ + i*69) * 16;
    #pragma unroll
    for (int k = 0; k < 4; ++k) {
        const int oidx = k*256 + t;
        const int w = oidx >> 4, cq = (oidx & 15) * 4;
        float4 vv;
        vv.x = tile[w][cq]; vv.y = tile[w][cq+1];
        vv.z = tile[w][cq+2]; vv.w = tile[w][cq+3];
        dst4[oidx] = vv;
    }
    for (int idx = t; idx < 320; idx += 256) {
        const int u = idx >> 6, cc = idx & 63;
        grid_t[((size_t)b*NIJ + i*69 + 64 + u)*64 + cc] =
            part_uv[((size_t)(b*5 + v)*5 + u)*64 + cc] * (1.f/4096.f);
    }
}

// ---------------------------------------------------------------------------
// K2: per-position MLP + region conv. 256 threads = 4 waves x 18 columns.
// __launch_bounds__(256, 1): weight arrays must stay in VGPRs (R2 lesson).
// ---------------------------------------------------------------------------
#define LOADROW(dst, src)                                              \
    { _Pragma("unroll")                                                \
      for (int q = 0; q < 16; ++q) {                                   \
          float4 t4 = ((const float4*)(src))[lane*16 + q];             \
          dst[4*q+0] = t4.x; dst[4*q+1] = t4.y;                        \
          dst[4*q+2] = t4.z; dst[4*q+3] = t4.w;                        \
      } }

#define DOT64(res, wr, src)                                            \
    float res;                                                         \
    { float _a0=0.f,_a1=0.f,_a2=0.f,_a3=0.f;                           \
      _Pragma("unroll")                                                \
      for (int cc2 = 0; cc2 < 64; cc2 += 4) {                          \
          _a0 = fmaf(wr[cc2+0], rdlane(src, cc2+0), _a0);              \
          _a1 = fmaf(wr[cc2+1], rdlane(src, cc2+1), _a1);              \
          _a2 = fmaf(wr[cc2+2], rdlane(src, cc2+2), _a2);              \
          _a3 = fmaf(wr[cc2+3], rdlane(src, cc2+3), _a3);              \
      }                                                                \
      res = (_a0 + _a1) + (_a2 + _a3); }

#define MLP_BODY(J)                                                    \
    {                                                                  \
        const int jj = (J);                                            \
        float v = gtb[(size_t)(i*69 + jj) * CC + lane];                \
        DOT64(d1, w1r, v);                                             \
        float acc1 = d1 + b1v;                                         \
        float ya = acc1 / (1.f + __expf(-acc1));                       \
        DOT64(d2, w2r, ya);                                            \
        float acc2 = d2 + b2v;                                         \
        DOT64(d3, fr, acc2);                                           \
        sp[(size_t)(jj - jbase) * sstr] = d3 + fbv;                    \
    }

__global__ __launch_bounds__(256, 1) void k2_mlp(
        const float* __restrict__ grid_t,
        const float* __restrict__ w1, const float* __restrict__ b1,
        const float* __restrict__ w2, const float* __restrict__ b2,
        const float* __restrict__ fw0, const float* __restrict__ fb0,
        const float* __restrict__ fw1, const float* __restrict__ fb1,
        const float* __restrict__ fw2, const float* __restrict__ fb2,
        const float* __restrict__ fw3, const float* __restrict__ fb3,
        float* __restrict__ mod_hw, float* __restrict__ mod_uh,
        float* __restrict__ mod_vw, float* __restrict__ mod_uv) {
    const int row  = blockIdx.x;          // 0..275
    const int b    = row / 69;
    const int i    = row % 69;
    const int wave = threadIdx.x >> 6;
    const int lane = threadIdx.x & 63;

    const int j0 = wave * 18;
    const int j1 = min(69, j0 + 18);
    const bool top = (i < 64);

    const float* fwA = top ? fw0 : fw3;
    const float* fbA = top ? fb0 : fb3;
    const float* fwB = top ? fw2 : fw1;
    const float* fbB = top ? fb2 : fb1;

    float w1r[64], w2r[64], fr[64];
    LOADROW(w1r, w1);
    LOADROW(w2r, w2);
    const float b1v = b1[lane];
    const float b2v = b2[lane];

    const float* gtb = grid_t + (size_t)b * NIJ * CC;
    const int cbl = b * CC + lane;

    const int jm = min(j1, 64);
    if (j0 < jm) {                        // region A: j < 64
        LOADROW(fr, fwA);
        const float fbv = fbA[lane];
        float* sp; int sstr; const int jbase = 0;
        if (top) { sp = mod_hw + ((size_t)cbl*64 + i)*64;          sstr = 1; }
        else     { sp = mod_vw + (size_t)cbl*320 + (i-64)*64;      sstr = 1; }
        for (int j = j0; j < jm; ++j) MLP_BODY(j)
    }
    if (j1 > 64) {                        // region B: j >= 64
        LOADROW(fr, fwB);
        const float fbv = fbB[lane];
        float* sp; int sstr; const int jbase = 64;
        if (top) { sp = mod_uh + (size_t)cbl*320 + i;              sstr = 64; }
        else     { sp = mod_uv + (size_t)cbl*25 + (i-64);          sstr = 5;  }
        const int jb = max(j0, 64);
        for (int j = jb; j < j1; ++j) MLP_BODY(j)
    }
}

// ---------------------------------------------------------------------------
// K3: out = x * (mod_hw + mod_uv + mod_uh + mod_vw)
// 1024 blocks = (bc, quarter), 256 threads. No LDS, no barrier.
// ---------------------------------------------------------------------------
__global__ __launch_bounds__(256) void k3_apply(
        const float* __restrict__ x,
        const float* __restrict__ mod_hw, const float* __restrict__ mod_uh,
        const float* __restrict__ mod_vw, const float* __restrict__ mod_uv,
        float* __restrict__ out) {
    const int blk  = blockIdx.x;          // bc*4 + quarter
    const int bc   = blk >> 2;
    const int qt   = blk & 3;
    const int t    = threadIdx.x;         // 0..255
    const int base = qt*256 + t;          // quad index in tile, 0..1023
    const int h    = base >> 4;           // 0..63

    float4 mh = ((const float4*)(mod_hw + (size_t)bc * 4096))[base];
    float uh[5];
    #pragma unroll
    for (int u = 0; u < 5; ++u) uh[u] = mod_uh[(size_t)bc*320 + u*64 + h];
    float4 vw[5];
    #pragma unroll
    for (int v = 0; v < 5; ++v)
        vw[v] = ((const float4*)(mod_vw + (size_t)bc*320 + v*64))[t & 15];
    float uv[25];
    #pragma unroll
    for (int k = 0; k < 25; ++k) uv[k] = mod_uv[(size_t)bc*25 + k];  // uniform

    const float4* x4 = (const float4*)(x + (size_t)bc * (UU*VV*HH*WW));
    float4* o4 = (float4*)(out + (size_t)bc * (UU*VV*HH*WW));

    #pragma unroll
    for (int u = 0; u < 5; ++u) {
        #pragma unroll
        for (int v = 0; v < 5; ++v) {
            const int idx = (u*5 + v)*1024 + base;
            float4 xv = x4[idx];
            const float s = uh[u] + uv[u*5 + v];
            float4 r;
            r.x = xv.x * (mh.x + vw[v].x + s);
            r.y = xv.y * (mh.y + vw[v].y + s);
            r.z = xv.z * (mh.z + vw[v].z + s);
            r.w = xv.w * (mh.w + vw[v].w + s);
            o4[idx] = r;
        }
    }
}

// ---------------------------------------------------------------------------
extern "C" void kernel_launch(void* const* d_in, const int* in_sizes, int n_in,
                              void* d_out, int out_size, void* d_ws, size_t ws_size,
                              hipStream_t stream) {
    const float* x   = (const float*)d_in[0];
    const float* w1  = (const float*)d_in[1];
    const float* b1  = (const float*)d_in[2];
    const float* w2  = (const float*)d_in[3];
    const float* b2  = (const float*)d_in[4];
    const float* fw0 = (const float*)d_in[5];
    const float* fb0 = (const float*)d_in[6];
    const float* fw1 = (const float*)d_in[7];
    const float* fb1 = (const float*)d_in[8];
    const float* fw2 = (const float*)d_in[9];
    const float* fb2 = (const float*)d_in[10];
    const float* fw3 = (const float*)d_in[11];
    const float* fb3 = (const float*)d_in[12];

    float* ws = (float*)d_ws;
    float* grid_t = ws;                        // 4*4761*64      = 1,218,816
    float* mod_hw = ws + 1218816;              // 256*4096       = 1,048,576
    float* mod_uh = mod_hw + 1048576;          // 256*320        =    81,920
    float* mod_vw = mod_uh + 81920;            // 256*320        =    81,920
    float* mod_uv = mod_vw + 81920;            // 256*25         =     6,400

    // d_out doubles as scratch for k1 partials (k3 fully rewrites it).
    float* part_hw = (float*)d_out;            // 1280*4096      = 5,242,880
    float* part_vw = part_hw + 5242880;        // 1280*320       =   409,600
    float* part_uv = part_vw + 409600;         // 100*64         =     6,400

    k1_means<<<BB*CC*UU, 512, 0, stream>>>(x, part_hw, part_vw, part_uv);
    k1b_top<<<BB*CC, 512, 0, stream>>>(part_hw, grid_t);
    k1b_bot<<<BB*VV, 256, 0, stream>>>(part_vw, part_uv, grid_t);
    k2_mlp<<<BB*69, 256, 0, stream>>>(grid_t, w1, b1, w2, b2,
                                      fw0, fb0, fw1, fb1, fw2, fb2, fw3, fb3,
                                      mod_hw, mod_uh, mod_vw, mod_uv);
    k3_apply<<<BB*CC*4, 256, 0, stream>>>(x, mod_hw, mod_uh, mod_vw, mod_uv,
                                          (float*)d_out);
}

// Round 7
// 108.063 us; speedup vs baseline: 1.0572x; 1.0572x over previous
//
#include <hip/hip_runtime.h>
#include <hip/hip_bf16.h>
#include <cstddef>

#define BB 4
#define CC 64
#define UU 5
#define VV 5
#define HH 64
#define WW 64
#define NIJ (69*69)   // 4761

__device__ __forceinline__ float rdlane(float v, int l) {
    return __uint_as_float((unsigned)__builtin_amdgcn_readlane((int)__float_as_uint(v), l));
}
__device__ __forceinline__ float sum4(float4 a) { return (a.x+a.y)+(a.z+a.w); }

// ---------------------------------------------------------------------------
// K1: grid = B*C*U = 1280 blocks, 512 threads. Pure-VALU inner loop;
// cross-lane reduction deferred to block end.
//   part_hw[(b*5+u)*64+c][h*16+wq]  f4, UNSCALED sum over v
//   part_vw[(b*5+u)*64+c][v*16+wq]  f4, UNSCALED col sums (over h)
//   part_uv[((b*5+v)*5+u)*64+c]     UNSCALED tile totals
// part_* live in d_out (scratch until k3 rewrites it).
// ---------------------------------------------------------------------------
__global__ __launch_bounds__(512) void k1_means(const float* __restrict__ x,
        float* __restrict__ part_hw, float* __restrict__ part_vw,
        float* __restrict__ part_uv) {
    const int blk = blockIdx.x;       // bc*5 + u
    const int bc  = blk / 5;
    const int u   = blk % 5;
    const int b   = bc >> 6;
    const int c   = bc & 63;
    const int pidx = (b*5 + u)*64 + c;
    const float4* xt = (const float4*)x + (size_t)bc * 25600 + (size_t)u * 5120;
    const int t    = threadIdx.x;     // 0..511
    const int wave = t >> 6;
    const int lane = t & 63;

    __shared__ float4 vw_lds[8][5][16];

    float4 A[5], B[5];
    #pragma unroll
    for (int v = 0; v < 5; ++v) {
        A[v] = xt[v*1024 + t];
        B[v] = xt[v*1024 + 512 + t];
    }

    float4 hw0 = make_float4(0.f,0.f,0.f,0.f);
    float4 hw1 = make_float4(0.f,0.f,0.f,0.f);
    float4 cs[5];
    #pragma unroll
    for (int v = 0; v < 5; ++v) {
        float4 a = A[v], d = B[v];
        hw0.x += a.x; hw0.y += a.y; hw0.z += a.z; hw0.w += a.w;
        hw1.x += d.x; hw1.y += d.y; hw1.z += d.z; hw1.w += d.w;
        cs[v].x = a.x + d.x; cs[v].y = a.y + d.y;
        cs[v].z = a.z + d.z; cs[v].w = a.w + d.w;
    }

    float4* ph4 = (float4*)part_hw + (size_t)pidx * 1024;
    ph4[t]       = hw0;
    ph4[512 + t] = hw1;

    #pragma unroll
    for (int v = 0; v < 5; ++v) {
        float4 s = cs[v];
        s.x += __shfl_xor(s.x, 16); s.y += __shfl_xor(s.y, 16);
        s.z += __shfl_xor(s.z, 16); s.w += __shfl_xor(s.w, 16);
        s.x += __shfl_xor(s.x, 32); s.y += __shfl_xor(s.y, 32);
        s.z += __shfl_xor(s.z, 32); s.w += __shfl_xor(s.w, 32);
        if (lane < 16) vw_lds[wave][v][lane] = s;
    }
    __syncthreads();

    if (t < 80) {   // v = t>>4, wq = t&15: cross-wave reduce
        const int v = t >> 4;
        float4 s = vw_lds[0][v][t & 15];
        #pragma unroll
        for (int w8 = 1; w8 < 8; ++w8) {
            float4 p = vw_lds[w8][v][t & 15];
            s.x += p.x; s.y += p.y; s.z += p.z; s.w += p.w;
        }
        ((float4*)part_vw)[(size_t)pidx*80 + t] = s;
        float hs = sum4(s);
        hs += __shfl_xor(hs, 1); hs += __shfl_xor(hs, 2);
        hs += __shfl_xor(hs, 4); hs += __shfl_xor(hs, 8);
        if ((t & 15) == 0)
            part_uv[((size_t)(b*5 + v)*5 + u)*64 + c] = hs;
    }
}

// ---------------------------------------------------------------------------
// K1b (merged top+bot): 276 blocks, 512 threads.
// blk<256: (b,h) top row -> sum part_hw over u, derive uh, transpose, write.
// blk>=256: (b,v) bottom row -> sum part_vw over u, transpose, uv border.
// ---------------------------------------------------------------------------
__global__ __launch_bounds__(512) void k1b_assemble(
        const float* __restrict__ part_hw, const float* __restrict__ part_vw,
        const float* __restrict__ part_uv, float* __restrict__ grid_t) {
    __shared__ float tile[64][68];
    const int blk = blockIdx.x;
    const bool top = blk < 256;
    const int t = threadIdx.x;        // 0..511
    const int c = t >> 3;             // 0..63
    const int q = t & 7;              // 0..7

    int b, i;
    if (top) {
        b = blk >> 6;
        const int h = blk & 63;
        i = h;
        float4 acc0 = make_float4(0.f,0.f,0.f,0.f);
        float4 acc1 = make_float4(0.f,0.f,0.f,0.f);
        float uhv[5];
        #pragma unroll
        for (int u = 0; u < 5; ++u) {
            const float4* src = (const float4*)part_hw
                + ((size_t)((b*5 + u)*64 + c)) * 1024 + h*16;
            float4 p0 = src[q];
            float4 p1 = src[8 + q];
            acc0.x += p0.x; acc0.y += p0.y; acc0.z += p0.z; acc0.w += p0.w;
            acc1.x += p1.x; acc1.y += p1.y; acc1.z += p1.z; acc1.w += p1.w;
            float uu = sum4(p0) + sum4(p1);
            uu += __shfl_xor(uu, 1); uu += __shfl_xor(uu, 2); uu += __shfl_xor(uu, 4);
            uhv[u] = uu;              // valid at q==0
        }
        const float s25 = 1.f/25.f;
        const int w0 = q*4, w1 = 32 + q*4;
        tile[w0+0][c] = acc0.x*s25; tile[w0+1][c] = acc0.y*s25;
        tile[w0+2][c] = acc0.z*s25; tile[w0+3][c] = acc0.w*s25;
        tile[w1+0][c] = acc1.x*s25; tile[w1+1][c] = acc1.y*s25;
        tile[w1+2][c] = acc1.z*s25; tile[w1+3][c] = acc1.w*s25;
        if (q == 0) {
            #pragma unroll
            for (int u = 0; u < 5; ++u)
                grid_t[((size_t)b*NIJ + h*69 + 64 + u)*64 + c] = uhv[u] * (1.f/320.f);
        }
    } else {
        b = (blk - 256) / 5;
        const int v = (blk - 256) % 5;
        i = 64 + v;
        float4 a0 = make_float4(0.f,0.f,0.f,0.f);
        float4 a1 = make_float4(0.f,0.f,0.f,0.f);
        #pragma unroll
        for (int u = 0; u < 5; ++u) {
            const float4* src = (const float4*)part_vw
                + ((size_t)((b*5 + u)*64 + c)) * 80 + v*16;
            float4 p0 = src[q];
            float4 p1 = src[8 + q];
            a0.x += p0.x; a0.y += p0.y; a0.z += p0.z; a0.w += p0.w;
            a1.x += p1.x; a1.y += p1.y; a1.z += p1.z; a1.w += p1.w;
        }
        const float sc = 1.f/320.f;
        const int w0 = q*4, w1 = 32 + q*4;
        tile[w0+0][c] = a0.x*sc; tile[w0+1][c] = a0.y*sc;
        tile[w0+2][c] = a0.z*sc; tile[w0+3][c] = a0.w*sc;
        tile[w1+0][c] = a1.x*sc; tile[w1+1][c] = a1.y*sc;
        tile[w1+2][c] = a1.z*sc; tile[w1+3][c] = a1.w*sc;
        if (t < 320) {
            const int u = t >> 6, cc = t & 63;
            grid_t[((size_t)b*NIJ + i*69 + 64 + u)*64 + cc] =
                part_uv[((size_t)(b*5 + v)*5 + u)*64 + cc] * (1.f/4096.f);
        }
    }
    __syncthreads();

    float4* dst4 = (float4*)grid_t + ((size_t)b*NIJ + i*69) * 16;
    #pragma unroll
    for (int k = 0; k < 2; ++k) {
        const int oidx = k*512 + t;   // 0..1023
        const int w = oidx >> 4, cq = (oidx & 15) * 4;
        float4 v;
        v.x = tile[w][cq]; v.y = tile[w][cq+1];
        v.z = tile[w][cq+2]; v.w = tile[w][cq+3];
        dst4[oidx] = v;
    }
}

// ---------------------------------------------------------------------------
// K2: per-position MLP + region conv.
// grid = 276 rows x 4 chunks = 1104 blocks, 64 threads (ONE wave, ~17 cols).
// All waves co-resident -> no straggler tail. __launch_bounds__(64,1):
// weight arrays stay in VGPRs (R2 lesson).
// ---------------------------------------------------------------------------
#define LOADROW(dst, src)                                              \
    { _Pragma("unroll")                                                \
      for (int q = 0; q < 16; ++q) {                                   \
          float4 t4 = ((const float4*)(src))[lane*16 + q];             \
          dst[4*q+0] = t4.x; dst[4*q+1] = t4.y;                        \
          dst[4*q+2] = t4.z; dst[4*q+3] = t4.w;                        \
      } }

#define DOT64(res, wr, src)                                            \
    float res;                                                         \
    { float _a0=0.f,_a1=0.f,_a2=0.f,_a3=0.f;                           \
      _Pragma("unroll")                                                \
      for (int cc2 = 0; cc2 < 64; cc2 += 4) {                          \
          _a0 = fmaf(wr[cc2+0], rdlane(src, cc2+0), _a0);              \
          _a1 = fmaf(wr[cc2+1], rdlane(src, cc2+1), _a1);              \
          _a2 = fmaf(wr[cc2+2], rdlane(src, cc2+2), _a2);              \
          _a3 = fmaf(wr[cc2+3], rdlane(src, cc2+3), _a3);              \
      }                                                                \
      res = (_a0 + _a1) + (_a2 + _a3); }

#define MLP_BODY(J)                                                    \
    {                                                                  \
        const int jj = (J);                                            \
        float v = gtb[(size_t)(i*69 + jj) * CC + lane];                \
        DOT64(d1, w1r, v);                                             \
        float acc1 = d1 + b1v;                                         \
        float ya = acc1 / (1.f + __expf(-acc1));                       \
        DOT64(d2, w2r, ya);                                            \
        float acc2 = d2 + b2v;                                         \
        DOT64(d3, fr, acc2);                                           \
        sp[(size_t)(jj - jbase) * sstr] = d3 + fbv;                    \
    }

__global__ __launch_bounds__(64, 1) void k2_mlp(
        const float* __restrict__ grid_t,
        const float* __restrict__ w1, const float* __restrict__ b1,
        const float* __restrict__ w2, const float* __restrict__ b2,
        const float* __restrict__ fw0, const float* __restrict__ fb0,
        const float* __restrict__ fw1, const float* __restrict__ fb1,
        const float* __restrict__ fw2, const float* __restrict__ fb2,
        const float* __restrict__ fw3, const float* __restrict__ fb3,
        float* __restrict__ mod_hw, float* __restrict__ mod_uh,
        float* __restrict__ mod_vw, float* __restrict__ mod_uv) {
    const int blk  = blockIdx.x;          // row*4 + chunk
    const int row  = blk >> 2;            // 0..275
    const int chnk = blk & 3;
    const int b    = row / 69;
    const int i    = row % 69;
    const int lane = threadIdx.x & 63;

    const int j0 = chnk * 18;
    const int j1 = min(69, j0 + 18);
    const bool top = (i < 64);

    const float* fwA = top ? fw0 : fw3;
    const float* fbA = top ? fb0 : fb3;
    const float* fwB = top ? fw2 : fw1;
    const float* fbB = top ? fb2 : fb1;

    float w1r[64], w2r[64], fr[64];
    LOADROW(w1r, w1);
    LOADROW(w2r, w2);
    const float b1v = b1[lane];
    const float b2v = b2[lane];

    const float* gtb = grid_t + (size_t)b * NIJ * CC;
    const int cbl = b * CC + lane;

    const int jm = min(j1, 64);
    if (j0 < jm) {                        // region A: j < 64
        LOADROW(fr, fwA);
        const float fbv = fbA[lane];
        float* sp; int sstr; const int jbase = 0;
        if (top) { sp = mod_hw + ((size_t)cbl*64 + i)*64;          sstr = 1; }
        else     { sp = mod_vw + (size_t)cbl*320 + (i-64)*64;      sstr = 1; }
        for (int j = j0; j < jm; ++j) MLP_BODY(j)
    }
    if (j1 > 64) {                        // region B: j >= 64
        LOADROW(fr, fwB);
        const float fbv = fbB[lane];
        float* sp; int sstr; const int jbase = 64;
        if (top) { sp = mod_uh + (size_t)cbl*320 + i;              sstr = 64; }
        else     { sp = mod_uv + (size_t)cbl*25 + (i-64);          sstr = 5;  }
        const int jb = max(j0, 64);
        for (int j = jb; j < j1; ++j) MLP_BODY(j)
    }
}

// ---------------------------------------------------------------------------
// K3: out = x * (mod_hw + mod_uv + mod_uh + mod_vw)
// 1024 blocks = (bc, quarter), 256 threads. No LDS, no barrier.
// ---------------------------------------------------------------------------
__global__ __launch_bounds__(256) void k3_apply(
        const float* __restrict__ x,
        const float* __restrict__ mod_hw, const float* __restrict__ mod_uh,
        const float* __restrict__ mod_vw, const float* __restrict__ mod_uv,
        float* __restrict__ out) {
    const int blk  = blockIdx.x;          // bc*4 + quarter
    const int bc   = blk >> 2;
    const int qt   = blk & 3;
    const int t    = threadIdx.x;         // 0..255
    const int base = qt*256 + t;          // quad index in tile, 0..1023
    const int h    = base >> 4;           // 0..63

    float4 mh = ((const float4*)(mod_hw + (size_t)bc * 4096))[base];
    float uh[5];
    #pragma unroll
    for (int u = 0; u < 5; ++u) uh[u] = mod_uh[(size_t)bc*320 + u*64 + h];
    float4 vw[5];
    #pragma unroll
    for (int v = 0; v < 5; ++v)
        vw[v] = ((const float4*)(mod_vw + (size_t)bc*320 + v*64))[t & 15];
    float uv[25];
    #pragma unroll
    for (int k = 0; k < 25; ++k) uv[k] = mod_uv[(size_t)bc*25 + k];  // uniform

    const float4* x4 = (const float4*)(x + (size_t)bc * (UU*VV*HH*WW));
    float4* o4 = (float4*)(out + (size_t)bc * (UU*VV*HH*WW));

    #pragma unroll
    for (int u = 0; u < 5; ++u) {
        #pragma unroll
        for (int v = 0; v < 5; ++v) {
            const int idx = (u*5 + v)*1024 + base;
            float4 xv = x4[idx];
            const float s = uh[u] + uv[u*5 + v];
            float4 r;
            r.x = xv.x * (mh.x + vw[v].x + s);
            r.y = xv.y * (mh.y + vw[v].y + s);
            r.z = xv.z * (mh.z + vw[v].z + s);
            r.w = xv.w * (mh.w + vw[v].w + s);
            o4[idx] = r;
        }
    }
}

// ---------------------------------------------------------------------------
extern "C" void kernel_launch(void* const* d_in, const int* in_sizes, int n_in,
                              void* d_out, int out_size, void* d_ws, size_t ws_size,
                              hipStream_t stream) {
    const float* x   = (const float*)d_in[0];
    const float* w1  = (const float*)d_in[1];
    const float* b1  = (const float*)d_in[2];
    const float* w2  = (const float*)d_in[3];
    const float* b2  = (const float*)d_in[4];
    const float* fw0 = (const float*)d_in[5];
    const float* fb0 = (const float*)d_in[6];
    const float* fw1 = (const float*)d_in[7];
    const float* fb1 = (const float*)d_in[8];
    const float* fw2 = (const float*)d_in[9];
    const float* fb2 = (const float*)d_in[10];
    const float* fw3 = (const float*)d_in[11];
    const float* fb3 = (const float*)d_in[12];

    float* ws = (float*)d_ws;
    float* grid_t = ws;                        // 4*4761*64      = 1,218,816
    float* mod_hw = ws + 1218816;              // 256*4096       = 1,048,576
    float* mod_uh = mod_hw + 1048576;          // 256*320        =    81,920
    float* mod_vw = mod_uh + 81920;            // 256*320        =    81,920
    float* mod_uv = mod_vw + 81920;            // 256*25         =     6,400

    // d_out doubles as scratch for k1 partials (k3 fully rewrites it).
    float* part_hw = (float*)d_out;            // 1280*4096      = 5,242,880
    float* part_vw = part_hw + 5242880;        // 1280*320       =   409,600
    float* part_uv = part_vw + 409600;         // 100*64         =     6,400

    k1_means<<<BB*CC*UU, 512, 0, stream>>>(x, part_hw, part_vw, part_uv);
    k1b_assemble<<<BB*CC + BB*VV, 512, 0, stream>>>(part_hw, part_vw, part_uv, grid_t);
    k2_mlp<<<BB*69*4, 64, 0, stream>>>(grid_t, w1, b1, w2, b2,
                                       fw0, fb0, fw1, fb1, fw2, fb2, fw3, fb3,
                                       mod_hw, mod_uh, mod_vw, mod_uv);
    k3_apply<<<BB*CC*4, 256, 0, stream>>>(x, mod_hw, mod_uh, mod_vw, mod_uv,
                                          (float*)d_out);
}